// Round 2
// baseline (263.834 us; speedup 1.0000x reference)
//
#include <hip/hip_runtime.h>

// Depthwise 2x2 Haar high-pass, stride 1, VALID.
// in:  (B=4, C=128, H=512, W=512) fp32
// out: (B,   C,     511,   511)   fp32
// out[y,x] = 0.5*(in[y,x] - in[y,x+1] - in[y+1,x] + in[y+1,x+1])
//
// Output rows have stride 511 -> naive float4 stores are misaligned.
// Here every vector store is 16B-aligned: lane t owns flat-aligned chunks
// starting at s = 8t + (p ? p-4 : 0), where p = (y - ch) & 3 is the row's
// alignment phase. Inputs come from the lane's own aligned 32B load plus
// one-lane shuffles. Row edges (<=3 elems) are scalar-stored by lanes 0/63.

#define Bn 4
#define Cn 128
#define Hn 512
#define Wn 512
#define OH 511
#define OW 511
#define RPW 32       // output rows per wave
#define TPB 256      // 4 waves per block

typedef float f4 __attribute__((ext_vector_type(4)));

__device__ __forceinline__ float haar(float t0, float t1, float b0, float b1) {
    return 0.5f * ((t0 - t1) - (b0 - b1));
}

template<int P>
__device__ __forceinline__ void do_row(
    float* __restrict__ op, int lane, int xi,
    const f4& tA, const f4& tB, float tP1, float tP2, float tP3, float tE,
    const f4& bA, const f4& bB, float bP1, float bP2, float bP3, float bE)
{
    // 9-element input windows for this lane's two output chunks.
    float t9[9], b9[9];
    if constexpr (P == 0) {
        t9[0]=tA.x; t9[1]=tA.y; t9[2]=tA.z; t9[3]=tA.w; t9[4]=tB.x; t9[5]=tB.y; t9[6]=tB.z; t9[7]=tB.w; t9[8]=tE;
        b9[0]=bA.x; b9[1]=bA.y; b9[2]=bA.z; b9[3]=bA.w; b9[4]=bB.x; b9[5]=bB.y; b9[6]=bB.z; b9[7]=bB.w; b9[8]=bE;
    } else if constexpr (P == 1) {
        t9[0]=tP1; t9[1]=tP2; t9[2]=tP3; t9[3]=tA.x; t9[4]=tA.y; t9[5]=tA.z; t9[6]=tA.w; t9[7]=tB.x; t9[8]=tB.y;
        b9[0]=bP1; b9[1]=bP2; b9[2]=bP3; b9[3]=bA.x; b9[4]=bA.y; b9[5]=bA.z; b9[6]=bA.w; b9[7]=bB.x; b9[8]=bB.y;
    } else if constexpr (P == 2) {
        t9[0]=tP2; t9[1]=tP3; t9[2]=tA.x; t9[3]=tA.y; t9[4]=tA.z; t9[5]=tA.w; t9[6]=tB.x; t9[7]=tB.y; t9[8]=tB.z;
        b9[0]=bP2; b9[1]=bP3; b9[2]=bA.x; b9[3]=bA.y; b9[4]=bA.z; b9[5]=bA.w; b9[6]=bB.x; b9[7]=bB.y; b9[8]=bB.z;
    } else {
        t9[0]=tP3; t9[1]=tA.x; t9[2]=tA.y; t9[3]=tA.z; t9[4]=tA.w; t9[5]=tB.x; t9[6]=tB.y; t9[7]=tB.z; t9[8]=tB.w;
        b9[0]=bP3; b9[1]=bA.x; b9[2]=bA.y; b9[3]=bA.z; b9[4]=bA.w; b9[5]=bB.x; b9[6]=bB.y; b9[7]=bB.z; b9[8]=bB.w;
    }

    float o0 = haar(t9[0], t9[1], b9[0], b9[1]);
    float o1 = haar(t9[1], t9[2], b9[1], b9[2]);
    float o2 = haar(t9[2], t9[3], b9[2], b9[3]);
    float o3 = haar(t9[3], t9[4], b9[3], b9[4]);
    float o4 = haar(t9[4], t9[5], b9[4], b9[5]);
    float o5 = haar(t9[5], t9[6], b9[5], b9[6]);
    float o6 = haar(t9[6], t9[7], b9[6], b9[7]);
    float o7 = haar(t9[7], t9[8], b9[7], b9[8]);

    const int sA = xi + (P == 0 ? 0 : P - 4);

    // Aligned vector stores (flat addr of op+sA is 16B aligned by construction).
    if (!(lane == 0 && P > 0)) {
        f4 oA = {o0, o1, o2, o3};
        *reinterpret_cast<f4*>(op + sA) = oA;
    }
    if (!(lane == 63 && P == 0)) {
        f4 oB = {o4, o5, o6, o7};
        *reinterpret_cast<f4*>(op + sA + 4) = oB;
    }

    // Row-head partial (lane 0, P>0): valid outputs e = 0..P-1 map to o[e+4-P].
    if (P > 0 && lane == 0) {
        if constexpr (P == 1) { op[0] = o3; }
        else if constexpr (P == 2) { op[0] = o2; op[1] = o3; }
        else { op[0] = o1; op[1] = o2; op[2] = o3; }
    }
    // Row-tail partial (lane 63).
    if (lane == 63) {
        if constexpr (P == 0) {
            // vector B skipped; elements 508..510 valid
            op[508] = o4; op[509] = o5; op[510] = o6;
        } else if constexpr (P == 1) {
            op[509] = haar(tB.y, tB.z, bB.y, bB.z);
            op[510] = haar(tB.z, tB.w, bB.z, bB.w);
        } else if constexpr (P == 2) {
            op[510] = haar(tB.z, tB.w, bB.z, bB.w);
        }
    }
}

__global__ __launch_bounds__(TPB)
void haar_kernel(const float* __restrict__ in, float* __restrict__ out) {
    const int bc   = blockIdx.y;               // 0 .. B*C-1
    const int wave = threadIdx.x >> 6;
    const int lane = threadIdx.x & 63;
    const int grp  = blockIdx.x * 4 + wave;    // 0 .. 15
    const int y0   = grp * RPW;
    if (y0 >= OH) return;
    const int ylim = (OH - y0 < RPW) ? (OH - y0) : RPW;

    const float* __restrict__ inCh  = in  + (size_t)bc * Hn * Wn;
    float* __restrict__       outCh = out + (size_t)bc * (OH * OW);

    const int xi = lane * 8;                   // this lane's 8 input columns

    // Load + shuffle top row (y0).
    const float* rt = inCh + (size_t)y0 * Wn + xi;
    f4 tA = *reinterpret_cast<const f4*>(rt);
    f4 tB = *reinterpret_cast<const f4*>(rt + 4);
    float tP1 = __shfl_up(tB.y, 1);
    float tP2 = __shfl_up(tB.z, 1);
    float tP3 = __shfl_up(tB.w, 1);
    float tE  = __shfl_down(tA.x, 1);

    for (int r = 0; r < ylim; ++r) {
        const int y = y0 + r;
        const unsigned p = ((unsigned)(y - bc)) & 3u;

        const float* rb = inCh + (size_t)(y + 1) * Wn + xi;
        f4 bA = *reinterpret_cast<const f4*>(rb);
        f4 bB = *reinterpret_cast<const f4*>(rb + 4);
        float bP1 = __shfl_up(bB.y, 1);
        float bP2 = __shfl_up(bB.z, 1);
        float bP3 = __shfl_up(bB.w, 1);
        float bE  = __shfl_down(bA.x, 1);

        float* op = outCh + (size_t)y * OW;
        switch (p) {
            case 0u: do_row<0>(op, lane, xi, tA, tB, tP1, tP2, tP3, tE, bA, bB, bP1, bP2, bP3, bE); break;
            case 1u: do_row<1>(op, lane, xi, tA, tB, tP1, tP2, tP3, tE, bA, bB, bP1, bP2, bP3, bE); break;
            case 2u: do_row<2>(op, lane, xi, tA, tB, tP1, tP2, tP3, tE, bA, bB, bP1, bP2, bP3, bE); break;
            default: do_row<3>(op, lane, xi, tA, tB, tP1, tP2, tP3, tE, bA, bB, bP1, bP2, bP3, bE); break;
        }

        tA = bA; tB = bB; tP1 = bP1; tP2 = bP2; tP3 = bP3; tE = bE;
    }
}

extern "C" void kernel_launch(void* const* d_in, const int* in_sizes, int n_in,
                              void* d_out, int out_size, void* d_ws, size_t ws_size,
                              hipStream_t stream) {
    const float* x = (const float*)d_in[0];
    float* out = (float*)d_out;

    dim3 grid(4, Bn * Cn);   // 4 wave-groups of 4 waves x 32 rows = 512 rows; 512 channels
    dim3 block(TPB);
    haar_kernel<<<grid, block, 0, stream>>>(x, out);
}

// Round 3
// 263.495 us; speedup vs baseline: 1.0013x; 1.0013x over previous
//
#include <hip/hip_runtime.h>

// Depthwise 2x2 Haar high-pass, stride 1, VALID.
// in:  (B=4, C=128, H=512, W=512) fp32
// out: (B,   C,     511,   511)   fp32
// out[y,x] = 0.5*(in[y,x] - in[y,x+1] - in[y+1,x] + in[y+1,x+1])
//
// Round-1 structure + depth-1 row prefetch: the load of row r+2 is issued
// BEFORE the compute/store of row r, so the s_waitcnt for the row being
// consumed is vmcnt(k>0) (k = stores + prefetch issued after it) and the
// per-iteration store drain (vmcnt(0)) disappears from the critical path.

#define Bn 4
#define Cn 128
#define Hn 512
#define Wn 512
#define OH (Hn - 1)
#define OW (Wn - 1)
#define ROWS 64      // output rows per block
#define TPB 128      // 128 threads * 4 cols = 512 cols

typedef float f4 __attribute__((ext_vector_type(4)));
typedef float f4u __attribute__((ext_vector_type(4), aligned(4)));  // 4B-aligned stores

__global__ __launch_bounds__(TPB)
void haar_kernel(const float* __restrict__ in, float* __restrict__ out) {
    const int ch      = blockIdx.y;            // 0 .. B*C-1
    const int rowTile = blockIdx.x;            // 0 .. 7
    const int x0      = threadIdx.x * 4;       // 0,4,...,508
    const int y0      = rowTile * ROWS;

    const float* __restrict__ inCh  = in  + (size_t)ch * Hn * Wn;
    float* __restrict__       outCh = out + (size_t)ch * OH * OW;

    const bool edgeLd = (x0 + 4 >= Wn);        // thread 127: no col 512
    const bool edgeSt = (x0 + 4 > OW);         // thread 127: cols 508..510 only

    // Prologue: rows y0 (t) and y0+1 (b) in registers.
    const float* rT = inCh + (size_t)y0 * Wn + x0;
    f4 t = *reinterpret_cast<const f4*>(rT);
    float te = edgeLd ? 0.0f : rT[4];

    const float* rB = inCh + (size_t)(y0 + 1) * Wn + x0;
    f4 b = *reinterpret_cast<const f4*>(rB);
    float be = edgeLd ? 0.0f : rB[4];

    const int ylim = (OH - y0 < ROWS) ? (OH - y0) : ROWS;

    for (int r = 0; r < ylim; ++r) {
        // ---- prefetch row y0+r+2 first (decouples from store drain) ----
        int yn = y0 + r + 2;
        if (yn > Hn - 1) yn = Hn - 1;          // harmless clamp re-read on tail
        const float* rN = inCh + (size_t)yn * Wn + x0;
        f4 n = *reinterpret_cast<const f4*>(rN);
        float ne = edgeLd ? 0.0f : rN[4];

        // ---- compute row r from t (top) and b (bottom) ----
        f4 o;
        o.x = 0.5f * ((t.x - t.y) - (b.x - b.y));
        o.y = 0.5f * ((t.y - t.z) - (b.y - b.z));
        o.z = 0.5f * ((t.z - t.w) - (b.z - b.w));
        o.w = 0.5f * ((t.w - te)  - (b.w - be));

        float* op = outCh + (size_t)(y0 + r) * OW + x0;
        if (!edgeSt) {
            *reinterpret_cast<f4u*>(op) = o;
        } else {
            op[0] = o.x; op[1] = o.y; op[2] = o.z;
        }

        // ---- rotate buffers ----
        t = b;  te = be;
        b = n;  be = ne;
    }
}

extern "C" void kernel_launch(void* const* d_in, const int* in_sizes, int n_in,
                              void* d_out, int out_size, void* d_ws, size_t ws_size,
                              hipStream_t stream) {
    const float* x = (const float*)d_in[0];
    float* out = (float*)d_out;

    dim3 grid((OH + ROWS - 1) / ROWS, Bn * Cn);  // (8, 512)
    dim3 block(TPB);
    haar_kernel<<<grid, block, 0, stream>>>(x, out);
}

// Round 4
// 256.143 us; speedup vs baseline: 1.0300x; 1.0287x over previous
//
#include <hip/hip_runtime.h>

// Depthwise 2x2 Haar high-pass, stride 1, VALID.
// in:  (B=4, C=128, H=512, W=512) fp32 -> out: (B, C, 511, 511) fp32
// out[y,x] = 0.5*((in[y,x]-in[y,x+1]) - (in[y+1,x]-in[y+1,x+1]))
//
// Round 4: group-of-8-row batched, ping-pong double-buffered streaming.
//  - 8 row-loads issued as one burst (deep MLP, batched read stream)
//  - compute+store one group while the other group's loads are in flight:
//    every vmcnt leaves ~24 younger ops outstanding -> stores never drain
//    on the critical path, loads have a full group of latency slack.
//  - non-temporal stores: write stream has zero reuse; don't pollute L2/L3.

#define Bn 4
#define Cn 128
#define Hn 512
#define Wn 512
#define OH 511
#define OW 511
#define ROWS 64      // output rows per block (8 groups of 8)
#define TPB 128      // 128 threads * 4 cols = 512 cols

typedef float f4 __attribute__((ext_vector_type(4)));
typedef float f4u __attribute__((ext_vector_type(4), aligned(4)));

__device__ __forceinline__ void load_row(const float* __restrict__ p, bool edgeLd,
                                         f4& v, float& e) {
    v = *reinterpret_cast<const f4*>(p);
    e = edgeLd ? 0.0f : p[4];
}

__device__ __forceinline__ f4 haar_row(const f4& t, float te, const f4& b, float be) {
    f4 o;
    o.x = 0.5f * ((t.x - t.y) - (b.x - b.y));
    o.y = 0.5f * ((t.y - t.z) - (b.y - b.z));
    o.z = 0.5f * ((t.z - t.w) - (b.z - b.w));
    o.w = 0.5f * ((t.w - te)  - (b.w - be));
    return o;
}

__global__ __launch_bounds__(TPB)
void haar_kernel(const float* __restrict__ in, float* __restrict__ out) {
    const int ch      = blockIdx.y;            // 0 .. B*C-1
    const int rowTile = blockIdx.x;            // 0 .. 7
    const int x0      = threadIdx.x * 4;       // 0,4,...,508
    const int y0      = rowTile * ROWS;

    const float* __restrict__ inCh  = in  + (size_t)ch * Hn * Wn + x0;
    float* __restrict__       outCh = out + (size_t)ch * (OH * OW) + x0;

    const bool edgeLd = (x0 + 4 >= Wn);        // thread 127
    const bool edgeSt = (x0 + 4 > OW);         // thread 127

    f4 A[8], B[8], carry;
    float eA[8], eB[8], ecarry;

    // Prologue: carry = input row y0; A = input rows y0+1 .. y0+8.
    load_row(inCh + (size_t)y0 * Wn, edgeLd, carry, ecarry);
#pragma unroll
    for (int i = 0; i < 8; ++i)
        load_row(inCh + (size_t)(y0 + 1 + i) * Wn, edgeLd, A[i], eA[i]);

    for (int gp = 0; gp < 8; gp += 2) {
        // ---- burst-load group gp+1 into B (input rows y0+8*(gp+1)+1+i, clamped) ----
#pragma unroll
        for (int i = 0; i < 8; ++i) {
            int yy = y0 + 8 * (gp + 1) + 1 + i;
            if (yy > Hn - 1) yy = Hn - 1;      // tail clamp (last tile only)
            load_row(inCh + (size_t)yy * Wn, edgeLd, B[i], eB[i]);
        }

        // ---- compute + NT-store group gp from [carry, A0..A7] ----
        {
            f4 t = carry; float te = ecarry;
#pragma unroll
            for (int i = 0; i < 8; ++i) {
                f4 o = haar_row(t, te, A[i], eA[i]);
                const int yr = y0 + 8 * gp + i;
                if (yr < OH) {                 // block-uniform; false only for last row of last tile
                    float* op = outCh + (size_t)yr * OW;
                    if (!edgeSt) {
                        __builtin_nontemporal_store(*(f4u*)&o, (f4u*)op);
                    } else {
                        __builtin_nontemporal_store(o.x, op + 0);
                        __builtin_nontemporal_store(o.y, op + 1);
                        __builtin_nontemporal_store(o.z, op + 2);
                    }
                }
                t = A[i]; te = eA[i];
            }
            carry = t; ecarry = te;            // copy of A7 (made before A reload)
        }

        // ---- burst-load group gp+2 into A (if any) ----
        if (gp + 2 < 8) {
#pragma unroll
            for (int i = 0; i < 8; ++i) {
                int yy = y0 + 8 * (gp + 2) + 1 + i;
                if (yy > Hn - 1) yy = Hn - 1;
                load_row(inCh + (size_t)yy * Wn, edgeLd, A[i], eA[i]);
            }
        }

        // ---- compute + NT-store group gp+1 from [carry, B0..B7] ----
        {
            f4 t = carry; float te = ecarry;
#pragma unroll
            for (int i = 0; i < 8; ++i) {
                f4 o = haar_row(t, te, B[i], eB[i]);
                const int yr = y0 + 8 * (gp + 1) + i;
                if (yr < OH) {
                    float* op = outCh + (size_t)yr * OW;
                    if (!edgeSt) {
                        __builtin_nontemporal_store(*(f4u*)&o, (f4u*)op);
                    } else {
                        __builtin_nontemporal_store(o.x, op + 0);
                        __builtin_nontemporal_store(o.y, op + 1);
                        __builtin_nontemporal_store(o.z, op + 2);
                    }
                }
                t = B[i]; te = eB[i];
            }
            carry = t; ecarry = te;            // copy of B7
        }
    }
}

extern "C" void kernel_launch(void* const* d_in, const int* in_sizes, int n_in,
                              void* d_out, int out_size, void* d_ws, size_t ws_size,
                              hipStream_t stream) {
    const float* x = (const float*)d_in[0];
    float* out = (float*)d_out;

    dim3 grid((OH + ROWS - 1) / ROWS, Bn * Cn);  // (8, 512)
    dim3 block(TPB);
    haar_kernel<<<grid, block, 0, stream>>>(x, out);
}